// Round 7
// baseline (287.627 us; speedup 1.0000x reference)
//
#include <hip/hip_runtime.h>

#pragma clang fp contract(off)

#define BATCH 16
#define NPTS  4096
#define KNN   32
#define NW    4                 // waves per block = candidate-chunk split factor
#define CHUNK (NPTS / NW)       // 1024 candidates per wave
#define CH    30
#define Q8    8                 // per-chunk list depth (union 4*8 = 32 -> t_cap bound)
#define FD    42                // per-(wave,lane) index-FIFO depth (u16 entries)
                                // slot FD is a per-lane trash slot (branchless push)

#define INF_F __builtin_inff()

// Order-preserving float->uint encoding for atomic max (handles negatives).
__device__ __forceinline__ unsigned enc_f32(float f) {
    unsigned u = __float_as_uint(f);
    return (u & 0x80000000u) ? ~u : (u | 0x80000000u);
}
__device__ __forceinline__ float dec_f32(unsigned e) {
    unsigned u = (e & 0x80000000u) ? (e & 0x7FFFFFFFu) : ~e;
    return __uint_as_float(u);
}

__device__ __forceinline__ float med3f(float a, float b, float c) {
#if __has_builtin(__builtin_amdgcn_fmed3f)
    return __builtin_amdgcn_fmed3f(a, b, c);
#else
    float r;
    asm("v_med3_f32 %0, %1, %2, %3" : "=v"(r) : "v"(a), "v"(b), "v"(c));
    return r;
#endif
}

// |p|^2 — ONE formula, used for the pw plane and qw alike.
__device__ __forceinline__ float sq3(float px, float py, float pz) {
    return __builtin_fmaf(px, px, __builtin_fmaf(py, py, pz * pz));
}
// Distance with precomputed pw: 5 VALU. Same expression in EVERY pass ->
// bit-identical d everywhere (explicit fma, immune to contraction).
__device__ __forceinline__ float distp(float qx, float qy, float qz, float qw,
                                       float px, float py, float pz, float pw) {
    float dt = __builtin_fmaf(qx, px, __builtin_fmaf(qy, py, qz * pz));
    return __builtin_fmaf(-2.0f, dt, qw + pw);
}

__global__ void init_pool_kernel(unsigned* __restrict__ pool) {
    int i = blockIdx.x * blockDim.x + threadIdx.x;
    if (i < BATCH * CH) pool[i] = 0u;   // 0 is below every encoded finite float
}

// Block: 256 threads = 4 waves. Lane l owns query (qg*64 + l); wave w scans
// candidate chunk [w*1024, w*1024+1024). Candidate xyz read straight from
// global (wave-uniform address -> broadcast L2 line); |p|^2 from an LDS plane.
__launch_bounds__(256, 4)
__global__ void knn_feat_kernel(const float* __restrict__ x,
                                unsigned* __restrict__ pool) {
    __shared__ float          pw_lds[NPTS];               // 16 KB
    __shared__ float          t8[NW * 64];                // 1 KB
    __shared__ unsigned short fifo[NW * (FD + 1) * 64];   // 21.5 KB (incl. trash slot)
    __shared__ unsigned char  cbs[NW * 64];               // 256 B

    const int b   = blockIdx.x >> 6;               // 64 query-groups per batch
    const int qg  = blockIdx.x & 63;
    const int tid = threadIdx.x;
    const int w   = tid >> 6;                      // wave id = chunk id
    const int l   = tid & 63;                      // lane = query slot
    const int q   = qg * 64 + l;
    const float* __restrict__ xb = x + (size_t)b * NPTS * 3;

    // Stage |p|^2 plane (deterministic same bits in every block).
    for (int i = tid; i < NPTS; i += 256)
        pw_lds[i] = sq3(xb[i * 3 + 0], xb[i * 3 + 1], xb[i * 3 + 2]);
    __syncthreads();

    const float qx = xb[q * 3 + 0], qy = xb[q * 3 + 1], qz = xb[q * 3 + 2];
    const float qw = pw_lds[q];                    // same bits as candidates' pw

    const float4* __restrict__ g4  = (const float4*)xb + (size_t)w * (CHUNK * 3 / 4);
    const float4* __restrict__ pw4 = (const float4*)pw_lds + (size_t)w * (CHUNK / 4);

    // ---- Pass 1: top-8 distance VALUES of my chunk (sorted asc). ----
    float arr[Q8];
#pragma unroll
    for (int j = 0; j < Q8; ++j) arr[j] = INF_F;

#define INSERT8(dv)                                            \
    {                                                          \
        _Pragma("unroll")                                      \
        for (int j = Q8 - 1; j >= 1; --j)                      \
            arr[j] = med3f(arr[j - 1], arr[j], (dv));          \
        arr[0] = fminf(arr[0], (dv));                          \
    }

#pragma unroll 2
    for (int m4 = 0; m4 < CHUNK / 4; ++m4) {
        float4 A = g4[3 * m4], B = g4[3 * m4 + 1], C = g4[3 * m4 + 2];
        float4 PW = pw4[m4];
        float d0 = distp(qx, qy, qz, qw, A.x, A.y, A.z, PW.x);
        float d1 = distp(qx, qy, qz, qw, A.w, B.x, B.y, PW.y);
        float d2 = distp(qx, qy, qz, qw, B.z, B.w, C.x, PW.z);
        float d3 = distp(qx, qy, qz, qw, C.y, C.z, C.w, PW.w);
        INSERT8(d0); INSERT8(d1); INSERT8(d2); INSERT8(d3);
    }
#undef INSERT8

    t8[w * 64 + l] = arr[Q8 - 1];
    __syncthreads();

    // t_cap >= true 32nd distance: union of 4 chunk-top-8s = 32 distinct points.
    const float t_cap = fmaxf(fmaxf(t8[0 * 64 + l], t8[1 * 64 + l]),
                              fmaxf(t8[2 * 64 + l], t8[3 * 64 + l]));

    // ---- Pass 2: branchless collect of chunk-local indices with d <= t_cap.
    // Push = unconditional ds_write to slot (taken ? cnt : FD); slot FD = trash.
    unsigned short* __restrict__ fw = fifo + (w * (FD + 1)) * 64 + l;
    int cnt = 0;
#pragma unroll 2
    for (int m4 = 0; m4 < CHUNK / 4; ++m4) {
        float4 A = g4[3 * m4], B = g4[3 * m4 + 1], C = g4[3 * m4 + 2];
        float4 PW = pw4[m4];
        float d0 = distp(qx, qy, qz, qw, A.x, A.y, A.z, PW.x);
        float d1 = distp(qx, qy, qz, qw, A.w, B.x, B.y, PW.y);
        float d2 = distp(qx, qy, qz, qw, B.z, B.w, C.x, PW.z);
        float d3 = distp(qx, qy, qz, qw, C.y, C.z, C.w, PW.w);
        int mb = m4 * 4;
        {
            bool t = (d0 <= t_cap) && (cnt < FD);
            fw[(t ? cnt : FD) * 64] = (unsigned short)(mb + 0);  cnt += t;
        }
        {
            bool t = (d1 <= t_cap) && (cnt < FD);
            fw[(t ? cnt : FD) * 64] = (unsigned short)(mb + 1);  cnt += t;
        }
        {
            bool t = (d2 <= t_cap) && (cnt < FD);
            fw[(t ? cnt : FD) * 64] = (unsigned short)(mb + 2);  cnt += t;
        }
        {
            bool t = (d3 <= t_cap) && (cnt < FD);
            fw[(t ? cnt : FD) * 64] = (unsigned short)(mb + 3);  cnt += t;
        }
    }
    cbs[w * 64 + l] = (unsigned char)cnt;
    __syncthreads();

    if (w != 0) return;   // no barriers past this point

    // ---- Phase 3 (wave 0): exact selection + stats over collected entries.
    // Branchless: wave-uniform bounds, inactive lanes read self (OOB-safe)
    // and get d = INF (falls through the med3 insert as a no-op).
    int cc[NW];
#pragma unroll
    for (int ww = 0; ww < NW; ++ww) cc[ww] = cbs[ww * 64 + l];
    int mc[NW];
#pragma unroll
    for (int ww = 0; ww < NW; ++ww) {
        int m = cc[ww];
#pragma unroll
        for (int off = 32; off >= 1; off >>= 1) {
            int o = __shfl_xor(m, off, 64);
            m = (o > m) ? o : m;
        }
        mc[ww] = m;
    }

    float a32[KNN];
#pragma unroll
    for (int j = 0; j < KNN; ++j) a32[j] = INF_F;

#pragma unroll
    for (int ww = 0; ww < NW; ++ww) {
        const unsigned short* __restrict__ fwp = fifo + (ww * (FD + 1)) * 64 + l;
        const int c = cc[ww];
#pragma unroll 2
        for (int i = 0; i < mc[ww]; ++i) {
            bool act = i < c;
            int idx = act ? ((int)fwp[i * 64] + ww * CHUNK) : q;
            const float* pp = xb + 3 * idx;
            float d = distp(qx, qy, qz, qw, pp[0], pp[1], pp[2], pw_lds[idx]);
            d = act ? d : INF_F;
#pragma unroll
            for (int j = KNN - 1; j >= 1; --j)
                a32[j] = med3f(a32[j - 1], a32[j], d);
            a32[0] = fminf(a32[0], d);
        }
    }
    const float thr = a32[KNN - 1];
    int c_lt = 0;
#pragma unroll
    for (int j = 0; j < KNN; ++j) c_lt += a32[j] < thr;
    const int need = KNN - c_lt;                   // ties to take, in index order

    float s0 = 0.f, s1 = 0.f, s2 = 0.f;
    float ss0 = 0.f, ss1 = 0.f, ss2 = 0.f;
    float mx0 = -INF_F, mx1 = -INF_F, mx2 = -INF_F;
    float mn0 =  INF_F, mn1 =  INF_F, mn2 =  INF_F;
    int eq_seen = 0;
#pragma unroll
    for (int ww = 0; ww < NW; ++ww) {              // (ww asc, i asc) = index order
        const unsigned short* __restrict__ fwp = fifo + (ww * (FD + 1)) * 64 + l;
        const int c = cc[ww];
#pragma unroll 2
        for (int i = 0; i < mc[ww]; ++i) {
            bool act = i < c;
            int idx = act ? ((int)fwp[i * 64] + ww * CHUNK) : q;
            const float* pp = xb + 3 * idx;
            float px = pp[0], py = pp[1], pz = pp[2];
            float d = distp(qx, qy, qz, qw, px, py, pz, pw_lds[idx]);
            d = act ? d : INF_F;                    // INF: is_eq/take auto-false
            bool is_eq = (d == thr);
            bool take = (d < thr) || (is_eq && eq_seen < need);
            eq_seen += is_eq ? 1 : 0;
            if (take) {
                float r0 = px - qx, r1 = py - qy, r2 = pz - qz;
                s0 += r0;  s1 += r1;  s2 += r2;
                ss0 += r0 * r0;  ss1 += r1 * r1;  ss2 += r2 * r2;
                mx0 = fmaxf(mx0, r0); mx1 = fmaxf(mx1, r1); mx2 = fmaxf(mx2, r2);
                mn0 = fminf(mn0, r0); mn1 = fminf(mn1, r1); mn2 = fminf(mn2, r2);
            }
        }
    }

    const float invk = 1.0f / (float)KNN;
    float mu0 = s0 * invk, mu1 = s1 * invk, mu2 = s2 * invk;
    float ex0 = ss0 * invk, ex1 = ss1 * invk, ex2 = ss2 * invk;
    float st0 = sqrtf(fmaxf(ex0 - mu0 * mu0, 0.f));
    float st1 = sqrtf(fmaxf(ex1 - mu1 * mu1, 0.f));
    float st2 = sqrtf(fmaxf(ex2 - mu2 * mu2, 0.f));
    float nrm = sqrtf(mu0 * mu0 + mu1 * mu1 + mu2 * mu2) + 1e-8f;
    float u0 = mu0 / nrm, u1 = mu1 / nrm, u2 = mu2 / nrm;
    float cr0 = qy * u2 - qz * u1;
    float cr1 = qz * u0 - qx * u2;
    float cr2 = qx * u1 - qy * u0;
    float mq0 = fmaxf(mx0 * mx0, mn0 * mn0);
    float mq1 = fmaxf(mx1 * mx1, mn1 * mn1);
    float mq2 = fmaxf(mx2 * mx2, mn2 * mn2);

    float f[CH] = { qx, qy, qz,
                    mu0, mu1, mu2,
                    mx0, mx1, mx2,
                    mn0, mn1, mn2,
                    st0, st1, st2,
                    qx - mu0, qy - mu1, qz - mu2,
                    u0, u1, u2,
                    cr0, cr1, cr2,
                    mq0, mq1, mq2,
                    ex0, ex1, ex2 };

#pragma unroll
    for (int c = 0; c < CH; ++c) {
        float v = f[c];
#pragma unroll
        for (int off = 32; off >= 1; off >>= 1)
            v = fmaxf(v, __shfl_xor(v, off, 64));
        if (l == 0)
            atomicMax(pool + b * CH + c, enc_f32(v));
    }
}

__global__ void final_mm_kernel(const unsigned* __restrict__ pool,
                                const float* __restrict__ W,
                                const float* __restrict__ bias,
                                float* __restrict__ out) {
    int t = blockIdx.x * blockDim.x + threadIdx.x;
    if (t >= BATCH * 32) return;
    int bb = t >> 5, e = t & 31;
    float acc = bias[e];
#pragma unroll
    for (int c = 0; c < CH; ++c)
        acc += dec_f32(pool[bb * CH + c]) * W[e * CH + c];
    out[bb * 32 + e] = acc;
}

extern "C" void kernel_launch(void* const* d_in, const int* in_sizes, int n_in,
                              void* d_out, int out_size, void* d_ws, size_t ws_size,
                              hipStream_t stream) {
    const float* x    = (const float*)d_in[0];   // [16, 4096, 3] f32
    const float* W    = (const float*)d_in[1];   // [32, 30] f32
    const float* bias = (const float*)d_in[2];   // [32] f32
    float*       out  = (float*)d_out;           // [16, 32] f32
    unsigned*    pool = (unsigned*)d_ws;         // [16, 30] encoded f32

    hipLaunchKernelGGL(init_pool_kernel, dim3(1), dim3(512), 0, stream, pool);
    hipLaunchKernelGGL(knn_feat_kernel, dim3(BATCH * (NPTS / 64)), dim3(256),
                       0, stream, x, pool);
    hipLaunchKernelGGL(final_mm_kernel, dim3(1), dim3(512), 0, stream, pool, W, bias, out);
}